// Round 9
// baseline (126.538 us; speedup 1.0000x reference)
//
#include <hip/hip_runtime.h>
#include <hip/hip_bf16.h>
#include <cstdint>
#include <cstddef>

// B=4, S=4096, D=1024, E=10, R=4, TOPK=2, SCALING=0.25
#define D_DIM 1024
#define E_NUM 10

typedef __attribute__((ext_vector_type(8))) short bf16x8;
typedef __attribute__((ext_vector_type(4))) float f32x4;
typedef unsigned short u16;
typedef unsigned int u32;

__device__ __forceinline__ u16 f2bf(float f) {
  union { float f; u32 u; } v; v.f = f;
  u32 r = v.u + 0x7fffu + ((v.u >> 16) & 1u);   // RNE
  return (u16)(r >> 16);
}
__device__ __forceinline__ float bf2f(u16 u) {
  union { u32 u; float f; } v; v.u = ((u32)u) << 16; return v.f;
}
__device__ __forceinline__ float dot4(float4 a, float4 b) {
  return a.x * b.x + a.y * b.y + a.z * b.z + a.w * b.w;
}

// ---------------- W_base fp32 -> bf16 (proven) ----------------
__global__ void conv_w(const float* __restrict__ W, u16* __restrict__ Wb) {
  const int i = (blockIdx.x * 256 + threadIdx.x) * 8;
  float4 a = *(const float4*)(W + i);
  float4 b = *(const float4*)(W + i + 4);
  *(ushort4*)(Wb + i)     = make_ushort4(f2bf(a.x), f2bf(a.y), f2bf(a.z), f2bf(a.w));
  *(ushort4*)(Wb + i + 4) = make_ushort4(f2bf(b.x), f2bf(b.y), f2bf(b.z), f2bf(b.w));
}

// ---------------- Bld[48][1024] bf16: rows 0-39 = lora_down, 40-47 = 0 ------
__global__ void prep_ldb(const float* __restrict__ ld, u16* __restrict__ Bld) {
  const int r = blockIdx.x;   // 48
  for (int c = threadIdx.x; c < D_DIM; c += 256)
    Bld[r * D_DIM + c] = (r < 40) ? f2bf(ld[r * D_DIM + c]) : (u16)0;
}

// ---------------- h via MFMA, 4-way k-split across waves (R8-proven) --------
__global__ __launch_bounds__(256)
void moe_prep_h(const float* __restrict__ x, const u16* __restrict__ Bld,
                float* __restrict__ h_all, u16* __restrict__ xb) {
  __shared__ u16 sX[4][16 * 64];
  __shared__ u16 sB[4][48 * 64];
  __shared__ float sP[4][3][16][17];

  const int tid = threadIdx.x, lane = tid & 63, w = tid >> 6;
  const int r0 = blockIdx.x * 16;
  const int kbase = w * 256;

  f32x4 acc[3] = {};

  float4 av[4];
#pragma unroll
  for (int i = 0; i < 2; ++i) {
    const int c = lane * 2 + i, row = c >> 3, kc = c & 7;
    const float* g = x + (size_t)(r0 + row) * D_DIM + kbase + kc * 8;
    av[i * 2]     = *(const float4*)g;
    av[i * 2 + 1] = *(const float4*)(g + 4);
  }

#pragma unroll 1
  for (int kt = 0; kt < 4; ++kt) {
    const int k0 = kbase + kt * 64;
#pragma unroll
    for (int i = 0; i < 6; ++i) {
      const int c = i * 64 + lane, row = c >> 3, kc = (c & 7) ^ (row & 7);
      __builtin_amdgcn_global_load_lds(
          (const __attribute__((address_space(1))) u32*)(Bld + (size_t)row * D_DIM + k0 + kc * 8),
          (__attribute__((address_space(3))) u32*)&sB[w][c * 8], 16, 0, 0);
    }
#pragma unroll
    for (int i = 0; i < 2; ++i) {
      const int c = lane * 2 + i, row = c >> 3, kc = c & 7;
      const float4 a = av[i * 2], b = av[i * 2 + 1];
      const ushort4 ha = make_ushort4(f2bf(a.x), f2bf(a.y), f2bf(a.z), f2bf(a.w));
      const ushort4 hb = make_ushort4(f2bf(b.x), f2bf(b.y), f2bf(b.z), f2bf(b.w));
      const int off = (row * 128 + kc * 16) ^ ((row & 7) << 4);
      *(ushort4*)((char*)sX[w] + off)     = ha;
      *(ushort4*)((char*)sX[w] + off + 8) = hb;
      if (xb) {
        u16* dst = xb + (size_t)(r0 + row) * D_DIM + k0 + kc * 8;
        *(ushort4*)dst       = ha;
        *(ushort4*)(dst + 4) = hb;
      }
    }
    __syncthreads();
    if (kt < 3) {
#pragma unroll
      for (int i = 0; i < 2; ++i) {
        const int c = lane * 2 + i, row = c >> 3, kc = c & 7;
        const float* g = x + (size_t)(r0 + row) * D_DIM + (k0 + 64) + kc * 8;
        av[i * 2]     = *(const float4*)g;
        av[i * 2 + 1] = *(const float4*)(g + 4);
      }
    }
#pragma unroll
    for (int kk = 0; kk < 2; ++kk) {
      const int kb = kk * 64 + ((lane >> 4) * 16);
      const int rA = lane & 15;
      const bf16x8 a0 = *(const bf16x8*)((const char*)sX[w] + ((rA * 128 + kb) ^ ((rA & 7) << 4)));
#pragma unroll
      for (int cf = 0; cf < 3; ++cf) {
        const int rB = cf * 16 + (lane & 15);
        const bf16x8 q = *(const bf16x8*)((const char*)sB[w] + ((rB * 128 + kb) ^ ((rB & 7) << 4)));
        acc[cf] = __builtin_amdgcn_mfma_f32_16x16x32_bf16(a0, q, acc[cf], 0, 0, 0);
      }
    }
    __syncthreads();
  }

#pragma unroll
  for (int cf = 0; cf < 3; ++cf)
#pragma unroll
    for (int j = 0; j < 4; ++j)
      sP[w][cf][(lane >> 4) * 4 + j][lane & 15] = acc[cf][j];
  __syncthreads();

  const int row = tid >> 4, c16 = tid & 15;
#pragma unroll
  for (int cf = 0; cf < 3; ++cf) {
    const int col = cf * 16 + c16;
    if (col < 40) {
      const float s = sP[0][cf][row][c16] + sP[1][cf][row][c16] +
                      sP[2][cf][row][c16] + sP[3][cf][row][c16];
      h_all[(size_t)(r0 + row) * 40 + col] = s;
    }
  }
}

// ---------------- gating: R7/R8 math, gW read direct (no LDS stage) ---------
__global__ __launch_bounds__(256, 2)
void moe_gate(const float* __restrict__ x, const float* __restrict__ gW,
              const float* __restrict__ gb, const float* __restrict__ h_all,
              int* __restrict__ ids, float* __restrict__ cvals) {
  const int tid = threadIdx.x, lane = tid & 63, w = tid >> 6;
  const int tb = blockIdx.x * 16 + w * 4;

  float4 xv[4][4];
#pragma unroll
  for (int tok = 0; tok < 4; ++tok)
#pragma unroll
    for (int j = 0; j < 4; ++j)
      xv[tok][j] = *(const float4*)(x + (size_t)(tb + tok) * D_DIM + j * 256 + lane * 4);

  float lg[4][E_NUM];
#pragma unroll
  for (int e = 0; e < E_NUM; ++e) {
    float a0 = 0.f, a1 = 0.f, a2 = 0.f, a3 = 0.f;
#pragma unroll
    for (int j = 0; j < 4; ++j) {
      const float4 wv = *(const float4*)(gW + e * D_DIM + j * 256 + lane * 4);
      a0 += dot4(xv[0][j], wv);
      a1 += dot4(xv[1][j], wv);
      a2 += dot4(xv[2][j], wv);
      a3 += dot4(xv[3][j], wv);
    }
#pragma unroll
    for (int o = 32; o; o >>= 1) {
      a0 += __shfl_xor(a0, o);
      a1 += __shfl_xor(a1, o);
      a2 += __shfl_xor(a2, o);
      a3 += __shfl_xor(a3, o);
    }
    const float be = gb[e];
    lg[0][e] = a0 + be;
    lg[1][e] = a1 + be;
    lg[2][e] = a2 + be;
    lg[3][e] = a3 + be;
  }

  if (lane < 4) {
    const int tok = lane, t = tb + tok;
    int e0 = 0; float v0 = lg[tok][0];
#pragma unroll
    for (int e = 1; e < E_NUM; ++e) if (lg[tok][e] > v0) { v0 = lg[tok][e]; e0 = e; }
    int e1 = -1; float v1 = -3.0e38f;
#pragma unroll
    for (int e = 0; e < E_NUM; ++e) if (e != e0 && lg[tok][e] > v1) { v1 = lg[tok][e]; e1 = e; }
    const float pp = expf(v1 - v0);
    const float inv = 1.f / (1.f + pp);
    const float s0 = inv * 0.25f, s1 = pp * inv * 0.25f;   // softmax * SCALING
    ids[t * 2] = e0; ids[t * 2 + 1] = e1;
    const float4 h0 = *(const float4*)(h_all + (size_t)t * 40 + e0 * 4);
    const float4 h1 = *(const float4*)(h_all + (size_t)t * 40 + e1 * 4);
    *(float4*)(cvals + t * 8)     = make_float4(h0.x * s0, h0.y * s0, h0.z * s0, h0.w * s0);
    *(float4*)(cvals + t * 8 + 4) = make_float4(h1.x * s1, h1.y * s1, h1.z * s1, h1.w * s1);
  }
}

// ---------------- main GEMM: 2-phase double-buffered (T3 minimum recipe) ----
// STAGE(next) issued BEFORE compute(cur); ONE __syncthreads per K-tile
// (its implicit vmcnt(0) drains stage loads that had 32 MFMA under them).
__global__ __launch_bounds__(256, 2)
void moe_gemm_2ph(const u16* __restrict__ xb, const u16* __restrict__ Wb,
                  const float* __restrict__ bias, const int* __restrict__ ids,
                  const float* __restrict__ cvals, const float* __restrict__ lup,
                  float* __restrict__ out) {
  __shared__ u16 Al[2][128 * 64];   // 2 x 16 KB
  __shared__ u16 Bl[2][128 * 64];   // 2 x 16 KB

  const int tid = threadIdx.x, lane = tid & 63, wid = tid >> 6;
  const int wm = wid >> 1, wn = wid & 1;
  const int p = blockIdx.x;
  const int cx = p & 7, q = p >> 3;
  const int nb = q & 7, mb = cx * 16 + (q >> 3);
  const int m0 = mb * 128, n0 = nb * 128;

  // staging address precompute (chunk-XOR source -> linear dest = swizzled)
  const int sc_row[4] = { (0 * 256 + tid) >> 3, (1 * 256 + tid) >> 3,
                          (2 * 256 + tid) >> 3, (3 * 256 + tid) >> 3 };
  const int sc_kc[4]  = { ((0 * 256 + tid) & 7) ^ (sc_row[0] & 7),
                          ((1 * 256 + tid) & 7) ^ (sc_row[1] & 7),
                          ((2 * 256 + tid) & 7) ^ (sc_row[2] & 7),
                          ((3 * 256 + tid) & 7) ^ (sc_row[3] & 7) };

  f32x4 acc[4][4] = {};

#define STAGE(buf, k0)                                                          \
  {                                                                             \
    _Pragma("unroll")                                                           \
    for (int i = 0; i < 4; ++i) {                                               \
      const int c = i * 256 + tid;                                              \
      __builtin_amdgcn_global_load_lds(                                         \
          (const __attribute__((address_space(1))) u32*)(xb +                   \
              (size_t)(m0 + sc_row[i]) * D_DIM + (k0) + sc_kc[i] * 8),          \
          (__attribute__((address_space(3))) u32*)&Al[buf][c * 8], 16, 0, 0);   \
    }                                                                           \
    _Pragma("unroll")                                                           \
    for (int i = 0; i < 4; ++i) {                                               \
      const int c = i * 256 + tid;                                              \
      __builtin_amdgcn_global_load_lds(                                         \
          (const __attribute__((address_space(1))) u32*)(Wb +                   \
              (size_t)(n0 + sc_row[i]) * D_DIM + (k0) + sc_kc[i] * 8),          \
          (__attribute__((address_space(3))) u32*)&Bl[buf][c * 8], 16, 0, 0);   \
    }                                                                           \
  }

  // prologue
  STAGE(0, 0);
  __syncthreads();

#pragma unroll 1
  for (int kt = 0; kt < 16; ++kt) {
    const int cur = kt & 1;
    if (kt < 15) STAGE(cur ^ 1, (kt + 1) * 64);   // overlap with compute below
#pragma unroll
    for (int kk = 0; kk < 2; ++kk) {
      bf16x8 af[4], bfr[4];
      const int kb = kk * 64 + ((lane >> 4) * 16);
#pragma unroll
      for (int m = 0; m < 4; ++m) {
        const int row = wm * 64 + m * 16 + (lane & 15);
        af[m] = *(const bf16x8*)((const char*)Al[cur] + ((row * 128 + kb) ^ ((row & 7) << 4)));
      }
#pragma unroll
      for (int n = 0; n < 4; ++n) {
        const int row = wn * 64 + n * 16 + (lane & 15);
        bfr[n] = *(const bf16x8*)((const char*)Bl[cur] + ((row * 128 + kb) ^ ((row & 7) << 4)));
      }
#pragma unroll
      for (int m = 0; m < 4; ++m)
#pragma unroll
        for (int n = 0; n < 4; ++n)
          acc[m][n] = __builtin_amdgcn_mfma_f32_16x16x32_bf16(af[m], bfr[n], acc[m][n], 0, 0, 0);
    }
    __syncthreads();   // implicit vmcnt(0)+lgkmcnt(0): next tile landed
  }
#undef STAGE

  const int rg = lane >> 4, cl = lane & 15;
  const int baser = m0 + wm * 64, basec = n0 + wn * 64;
  float bs[4];
#pragma unroll
  for (int n = 0; n < 4; ++n) bs[n] = bias[basec + n * 16 + cl];
#pragma unroll
  for (int m = 0; m < 4; ++m)
#pragma unroll
    for (int j = 0; j < 4; ++j) {
      const int rr = baser + m * 16 + rg * 4 + j;
      const int2 id2 = *(const int2*)(ids + rr * 2);
      const float4 c0 = *(const float4*)(cvals + rr * 8);
      const float4 c1 = *(const float4*)(cvals + rr * 8 + 4);
      const float* u0b = lup + (size_t)id2.x * (D_DIM * 4);
      const float* u1b = lup + (size_t)id2.y * (D_DIM * 4);
#pragma unroll
      for (int n = 0; n < 4; ++n) {
        const int cc = basec + n * 16 + cl;
        float4 u0 = *(const float4*)(u0b + cc * 4);
        float4 u1 = *(const float4*)(u1b + cc * 4);
        float v = acc[m][n][j] + bs[n];
        v += c0.x * u0.x + c0.y * u0.y + c0.z * u0.z + c0.w * u0.w;
        v += c1.x * u1.x + c1.y * u1.y + c1.z * u1.z + c1.w * u1.w;
        out[(size_t)rr * D_DIM + cc] = v;
      }
    }
}

// ---------------- fallback GEMM (fp32 A, reg-staged) — R7-proven ------------
__global__ __launch_bounds__(256, 2)
void moe_gemm_f32(const float* __restrict__ x, const u16* __restrict__ Wb,
                  const float* __restrict__ bias, const int* __restrict__ ids,
                  const float* __restrict__ cvals, const float* __restrict__ lup,
                  float* __restrict__ out) {
  __shared__ u16 Al[128 * 64];
  __shared__ u16 Bl[128 * 64];
  const int tid = threadIdx.x, lane = tid & 63, wid = tid >> 6;
  const int wm = wid >> 1, wn = wid & 1;
  const int p = blockIdx.x;
  const int cx = p & 7, q = p >> 3;
  const int nb = q & 7, mb = cx * 16 + (q >> 3);
  const int m0 = mb * 128, n0 = nb * 128;
  f32x4 acc[4][4] = {};
  float4 av[8];
#pragma unroll
  for (int t = 0; t < 8; ++t) {
    int c = t * 256 + tid, row = c >> 4, k4 = c & 15;
    av[t] = *(const float4*)(x + (size_t)(m0 + row) * D_DIM + k4 * 4);
  }
#pragma unroll 1
  for (int kt = 0; kt < 16; ++kt) {
    const int k0 = kt * 64;
#pragma unroll
    for (int i = 0; i < 4; ++i) {
      int c = i * 256 + tid, row = c >> 3, kc = (c & 7) ^ (row & 7);
      __builtin_amdgcn_global_load_lds(
          (const __attribute__((address_space(1))) u32*)(Wb + (size_t)(n0 + row) * D_DIM + k0 + kc * 8),
          (__attribute__((address_space(3))) u32*)&Bl[c * 8], 16, 0, 0);
    }
#pragma unroll
    for (int t = 0; t < 8; ++t) {
      int c = t * 256 + tid, row = c >> 4, k4 = c & 15;
      int off = (row * 128 + k4 * 8) ^ ((row & 7) << 4);
      *(ushort4*)((char*)Al + off) =
          make_ushort4(f2bf(av[t].x), f2bf(av[t].y), f2bf(av[t].z), f2bf(av[t].w));
    }
    __syncthreads();
    if (kt < 15) {
#pragma unroll
      for (int t = 0; t < 8; ++t) {
        int c = t * 256 + tid, row = c >> 4, k4 = c & 15;
        av[t] = *(const float4*)(x + (size_t)(m0 + row) * D_DIM + (k0 + 64) + k4 * 4);
      }
    }
#pragma unroll
    for (int kk = 0; kk < 2; ++kk) {
      bf16x8 af[4], bfr[4];
      const int kb = kk * 64 + ((lane >> 4) * 16);
#pragma unroll
      for (int m = 0; m < 4; ++m) {
        int row = wm * 64 + m * 16 + (lane & 15);
        af[m] = *(const bf16x8*)((const char*)Al + ((row * 128 + kb) ^ ((row & 7) << 4)));
      }
#pragma unroll
      for (int n = 0; n < 4; ++n) {
        int row = wn * 64 + n * 16 + (lane & 15);
        bfr[n] = *(const bf16x8*)((const char*)Bl + ((row * 128 + kb) ^ ((row & 7) << 4)));
      }
#pragma unroll
      for (int m = 0; m < 4; ++m)
#pragma unroll
        for (int n = 0; n < 4; ++n)
          acc[m][n] = __builtin_amdgcn_mfma_f32_16x16x32_bf16(af[m], bfr[n], acc[m][n], 0, 0, 0);
    }
    __syncthreads();
  }
  const int rg = lane >> 4, cl = lane & 15;
  const int baser = m0 + wm * 64, basec = n0 + wn * 64;
  float bs[4];
#pragma unroll
  for (int n = 0; n < 4; ++n) bs[n] = bias[basec + n * 16 + cl];
#pragma unroll
  for (int m = 0; m < 4; ++m)
#pragma unroll
    for (int j = 0; j < 4; ++j) {
      const int rr = baser + m * 16 + rg * 4 + j;
      const int2 id2 = *(const int2*)(ids + rr * 2);
      const float4 c0 = *(const float4*)(cvals + rr * 8);
      const float4 c1 = *(const float4*)(cvals + rr * 8 + 4);
      const float* u0b = lup + (size_t)id2.x * (D_DIM * 4);
      const float* u1b = lup + (size_t)id2.y * (D_DIM * 4);
#pragma unroll
      for (int n = 0; n < 4; ++n) {
        const int cc = basec + n * 16 + cl;
        float4 u0 = *(const float4*)(u0b + cc * 4);
        float4 u1 = *(const float4*)(u1b + cc * 4);
        float v = acc[m][n][j] + bs[n];
        v += c0.x * u0.x + c0.y * u0.y + c0.z * u0.z + c0.w * u0.w;
        v += c1.x * u1.x + c1.y * u1.y + c1.z * u1.z + c1.w * u1.w;
        out[(size_t)rr * D_DIM + cc] = v;
      }
    }
}

extern "C" void kernel_launch(void* const* d_in, const int* in_sizes, int n_in,
                              void* d_out, int out_size, void* d_ws, size_t ws_size,
                              hipStream_t stream) {
  const float* x   = (const float*)d_in[0];
  const float* Wb_ = (const float*)d_in[1];
  const float* bb  = (const float*)d_in[2];
  const float* gW  = (const float*)d_in[3];
  const float* gb  = (const float*)d_in[4];
  const float* ld  = (const float*)d_in[5];
  const float* lup = (const float*)d_in[6];

  // ws (KB): Wbf 0-2048 | Bld 2048-2144 | ids 2144-2272 | cvals 2272-2784 |
  //          h_all 2784-5344 | xb 5632-38400  (~37.5 MB total)
  char* w = (char*)d_ws;
  u16*   Wbf   = (u16*)w;
  u16*   Bld   = (u16*)(w + 2048ull * 1024);
  int*   ids   = (int*)(w + 2144ull * 1024);
  float* cvals = (float*)(w + 2272ull * 1024);
  float* h_all = (float*)(w + 2784ull * 1024);
  const size_t need_full = (5632ull + 32768ull) * 1024;
  const bool full = ws_size >= need_full;
  u16* xb = full ? (u16*)(w + 5632ull * 1024) : nullptr;

  hipLaunchKernelGGL(conv_w,     dim3(512),  dim3(256), 0, stream, Wb_, Wbf);
  hipLaunchKernelGGL(prep_ldb,   dim3(48),   dim3(256), 0, stream, ld, Bld);
  hipLaunchKernelGGL(moe_prep_h, dim3(1024), dim3(256), 0, stream, x, Bld, h_all, xb);
  hipLaunchKernelGGL(moe_gate,   dim3(1024), dim3(256), 0, stream, x, gW, gb, h_all, ids, cvals);
  if (full)
    hipLaunchKernelGGL(moe_gemm_2ph, dim3(1024), dim3(256), 0, stream,
                       xb, Wbf, bb, ids, cvals, lup, (float*)d_out);
  else
    hipLaunchKernelGGL(moe_gemm_f32, dim3(1024), dim3(256), 0, stream,
                       x, Wbf, bb, ids, cvals, lup, (float*)d_out);
}

// Round 10
// 125.410 us; speedup vs baseline: 1.0090x; 1.0090x over previous
//
#include <hip/hip_runtime.h>
#include <hip/hip_bf16.h>
#include <cstdint>
#include <cstddef>

// B=4, S=4096, D=1024, E=10, R=4, TOPK=2, SCALING=0.25
#define D_DIM 1024
#define E_NUM 10

typedef __attribute__((ext_vector_type(8))) short bf16x8;
typedef __attribute__((ext_vector_type(4))) float f32x4;
typedef unsigned short u16;
typedef unsigned int u32;

__device__ __forceinline__ u16 f2bf(float f) {
  union { float f; u32 u; } v; v.f = f;
  u32 r = v.u + 0x7fffu + ((v.u >> 16) & 1u);   // RNE
  return (u16)(r >> 16);
}
__device__ __forceinline__ float bf2f(u16 u) {
  union { u32 u; float f; } v; v.u = ((u32)u) << 16; return v.f;
}
__device__ __forceinline__ float dot4(float4 a, float4 b) {
  return a.x * b.x + a.y * b.y + a.z * b.z + a.w * b.w;
}

// ---------------- W_base fp32 -> bf16 (proven) ----------------
__global__ void conv_w(const float* __restrict__ W, u16* __restrict__ Wb) {
  const int i = (blockIdx.x * 256 + threadIdx.x) * 8;
  float4 a = *(const float4*)(W + i);
  float4 b = *(const float4*)(W + i + 4);
  *(ushort4*)(Wb + i)     = make_ushort4(f2bf(a.x), f2bf(a.y), f2bf(a.z), f2bf(a.w));
  *(ushort4*)(Wb + i + 4) = make_ushort4(f2bf(b.x), f2bf(b.y), f2bf(b.z), f2bf(b.w));
}

// ---------------- Bld[48][1024] bf16: rows 0-39 = lora_down, 40-47 = 0 ------
__global__ void prep_ldb(const float* __restrict__ ld, u16* __restrict__ Bld) {
  const int r = blockIdx.x;   // 48
  for (int c = threadIdx.x; c < D_DIM; c += 256)
    Bld[r * D_DIM + c] = (r < 40) ? f2bf(ld[r * D_DIM + c]) : (u16)0;
}

// ---------------- h via MFMA, 4-way k-split across waves (R8-proven) --------
__global__ __launch_bounds__(256)
void moe_prep_h(const float* __restrict__ x, const u16* __restrict__ Bld,
                float* __restrict__ h_all, u16* __restrict__ xb) {
  __shared__ u16 sX[4][16 * 64];
  __shared__ u16 sB[4][48 * 64];
  __shared__ float sP[4][3][16][17];

  const int tid = threadIdx.x, lane = tid & 63, w = tid >> 6;
  const int r0 = blockIdx.x * 16;
  const int kbase = w * 256;

  f32x4 acc[3] = {};

  float4 av[4];
#pragma unroll
  for (int i = 0; i < 2; ++i) {
    const int c = lane * 2 + i, row = c >> 3, kc = c & 7;
    const float* g = x + (size_t)(r0 + row) * D_DIM + kbase + kc * 8;
    av[i * 2]     = *(const float4*)g;
    av[i * 2 + 1] = *(const float4*)(g + 4);
  }

#pragma unroll 1
  for (int kt = 0; kt < 4; ++kt) {
    const int k0 = kbase + kt * 64;
#pragma unroll
    for (int i = 0; i < 6; ++i) {
      const int c = i * 64 + lane, row = c >> 3, kc = (c & 7) ^ (row & 7);
      __builtin_amdgcn_global_load_lds(
          (const __attribute__((address_space(1))) u32*)(Bld + (size_t)row * D_DIM + k0 + kc * 8),
          (__attribute__((address_space(3))) u32*)&sB[w][c * 8], 16, 0, 0);
    }
#pragma unroll
    for (int i = 0; i < 2; ++i) {
      const int c = lane * 2 + i, row = c >> 3, kc = c & 7;
      const float4 a = av[i * 2], b = av[i * 2 + 1];
      const ushort4 ha = make_ushort4(f2bf(a.x), f2bf(a.y), f2bf(a.z), f2bf(a.w));
      const ushort4 hb = make_ushort4(f2bf(b.x), f2bf(b.y), f2bf(b.z), f2bf(b.w));
      const int off = (row * 128 + kc * 16) ^ ((row & 7) << 4);
      *(ushort4*)((char*)sX[w] + off)     = ha;
      *(ushort4*)((char*)sX[w] + off + 8) = hb;
      if (xb) {
        u16* dst = xb + (size_t)(r0 + row) * D_DIM + k0 + kc * 8;
        *(ushort4*)dst       = ha;
        *(ushort4*)(dst + 4) = hb;
      }
    }
    __syncthreads();
    if (kt < 3) {
#pragma unroll
      for (int i = 0; i < 2; ++i) {
        const int c = lane * 2 + i, row = c >> 3, kc = c & 7;
        const float* g = x + (size_t)(r0 + row) * D_DIM + (k0 + 64) + kc * 8;
        av[i * 2]     = *(const float4*)g;
        av[i * 2 + 1] = *(const float4*)(g + 4);
      }
    }
#pragma unroll
    for (int kk = 0; kk < 2; ++kk) {
      const int kb = kk * 64 + ((lane >> 4) * 16);
      const int rA = lane & 15;
      const bf16x8 a0 = *(const bf16x8*)((const char*)sX[w] + ((rA * 128 + kb) ^ ((rA & 7) << 4)));
#pragma unroll
      for (int cf = 0; cf < 3; ++cf) {
        const int rB = cf * 16 + (lane & 15);
        const bf16x8 q = *(const bf16x8*)((const char*)sB[w] + ((rB * 128 + kb) ^ ((rB & 7) << 4)));
        acc[cf] = __builtin_amdgcn_mfma_f32_16x16x32_bf16(a0, q, acc[cf], 0, 0, 0);
      }
    }
    __syncthreads();
  }

#pragma unroll
  for (int cf = 0; cf < 3; ++cf)
#pragma unroll
    for (int j = 0; j < 4; ++j)
      sP[w][cf][(lane >> 4) * 4 + j][lane & 15] = acc[cf][j];
  __syncthreads();

  const int row = tid >> 4, c16 = tid & 15;
#pragma unroll
  for (int cf = 0; cf < 3; ++cf) {
    const int col = cf * 16 + c16;
    if (col < 40) {
      const float s = sP[0][cf][row][c16] + sP[1][cf][row][c16] +
                      sP[2][cf][row][c16] + sP[3][cf][row][c16];
      h_all[(size_t)(r0 + row) * 40 + col] = s;
    }
  }
}

// ---------------- gating (R9-proven fp32 math, gW direct) -------------------
__global__ __launch_bounds__(256, 2)
void moe_gate(const float* __restrict__ x, const float* __restrict__ gW,
              const float* __restrict__ gb, const float* __restrict__ h_all,
              int* __restrict__ ids, float* __restrict__ cvals) {
  const int tid = threadIdx.x, lane = tid & 63, w = tid >> 6;
  const int tb = blockIdx.x * 16 + w * 4;

  float4 xv[4][4];
#pragma unroll
  for (int tok = 0; tok < 4; ++tok)
#pragma unroll
    for (int j = 0; j < 4; ++j)
      xv[tok][j] = *(const float4*)(x + (size_t)(tb + tok) * D_DIM + j * 256 + lane * 4);

  float lg[4][E_NUM];
#pragma unroll
  for (int e = 0; e < E_NUM; ++e) {
    float a0 = 0.f, a1 = 0.f, a2 = 0.f, a3 = 0.f;
#pragma unroll
    for (int j = 0; j < 4; ++j) {
      const float4 wv = *(const float4*)(gW + e * D_DIM + j * 256 + lane * 4);
      a0 += dot4(xv[0][j], wv);
      a1 += dot4(xv[1][j], wv);
      a2 += dot4(xv[2][j], wv);
      a3 += dot4(xv[3][j], wv);
    }
#pragma unroll
    for (int o = 32; o; o >>= 1) {
      a0 += __shfl_xor(a0, o);
      a1 += __shfl_xor(a1, o);
      a2 += __shfl_xor(a2, o);
      a3 += __shfl_xor(a3, o);
    }
    const float be = gb[e];
    lg[0][e] = a0 + be;
    lg[1][e] = a1 + be;
    lg[2][e] = a2 + be;
    lg[3][e] = a3 + be;
  }

  if (lane < 4) {
    const int tok = lane, t = tb + tok;
    int e0 = 0; float v0 = lg[tok][0];
#pragma unroll
    for (int e = 1; e < E_NUM; ++e) if (lg[tok][e] > v0) { v0 = lg[tok][e]; e0 = e; }
    int e1 = -1; float v1 = -3.0e38f;
#pragma unroll
    for (int e = 0; e < E_NUM; ++e) if (e != e0 && lg[tok][e] > v1) { v1 = lg[tok][e]; e1 = e; }
    const float pp = expf(v1 - v0);
    const float inv = 1.f / (1.f + pp);
    const float s0 = inv * 0.25f, s1 = pp * inv * 0.25f;   // softmax * SCALING
    ids[t * 2] = e0; ids[t * 2 + 1] = e1;
    const float4 h0 = *(const float4*)(h_all + (size_t)t * 40 + e0 * 4);
    const float4 h1 = *(const float4*)(h_all + (size_t)t * 40 + e1 * 4);
    *(float4*)(cvals + t * 8)     = make_float4(h0.x * s0, h0.y * s0, h0.z * s0, h0.w * s0);
    *(float4*)(cvals + t * 8 + 4) = make_float4(h1.x * s1, h1.y * s1, h1.z * s1, h1.w * s1);
  }
}

// ---------------- main GEMM: 256x256 tile, 8 waves, counted-vmcnt pipeline --
// Depth-2 prefetch, raw s_barrier + s_waitcnt vmcnt(8) (never 0 in steady
// state). STAGE(kt+2) issued after the read-done barrier (overwrite-safe).
__global__ __launch_bounds__(512, 2)
void moe_gemm_256(const u16* __restrict__ xb, const u16* __restrict__ Wb,
                  const float* __restrict__ bias, const int* __restrict__ ids,
                  const float* __restrict__ cvals, const float* __restrict__ lup,
                  float* __restrict__ out) {
  __shared__ u16 Al[2][256 * 64];   // 2 x 32 KB
  __shared__ u16 Bl[2][256 * 64];   // 2 x 32 KB  (128 KB total)

  const int tid = threadIdx.x, lane = tid & 63, wid = tid >> 6;
  const int wm = wid >> 2, wn = wid & 3;          // 2 x 4 wave grid
  const int p = blockIdx.x;                        // 256 blocks = 1/CU
  const int cx = p & 7, q = p >> 3;                // XCD, 32 blocks each
  const int nb = q & 3, mb = cx * 8 + (q >> 2);    // all 4 col-panels per XCD
  const int m0 = mb * 256, n0 = nb * 256;

  // staging source addresses (chunk-XOR source -> linear dest = swizzled LDS)
  int sc_row[4], sc_kc[4];
#pragma unroll
  for (int i = 0; i < 4; ++i) {
    const int c = i * 512 + tid;
    sc_row[i] = c >> 3;
    sc_kc[i]  = (c & 7) ^ (sc_row[i] & 7);
  }

  f32x4 acc[8][4] = {};

#define STAGE(buf, k0)                                                          \
  {                                                                             \
    _Pragma("unroll")                                                           \
    for (int i = 0; i < 4; ++i) {                                               \
      const int c = i * 512 + tid;                                              \
      __builtin_amdgcn_global_load_lds(                                         \
          (const __attribute__((address_space(1))) u32*)(xb +                   \
              (size_t)(m0 + sc_row[i]) * D_DIM + (k0) + sc_kc[i] * 8),          \
          (__attribute__((address_space(3))) u32*)&Al[buf][c * 8], 16, 0, 0);   \
    }                                                                           \
    _Pragma("unroll")                                                           \
    for (int i = 0; i < 4; ++i) {                                               \
      const int c = i * 512 + tid;                                              \
      __builtin_amdgcn_global_load_lds(                                         \
          (const __attribute__((address_space(1))) u32*)(Wb +                   \
              (size_t)(n0 + sc_row[i]) * D_DIM + (k0) + sc_kc[i] * 8),          \
          (__attribute__((address_space(3))) u32*)&Bl[buf][c * 8], 16, 0, 0);   \
    }                                                                           \
  }

  STAGE(0, 0);
  STAGE(1, 64);                                    // 16 loads in flight

#pragma unroll 1
  for (int kt = 0; kt < 16; ++kt) {
    const int cur = kt & 1;
    if (kt < 15) { asm volatile("s_waitcnt vmcnt(8)" ::: "memory"); }
    else         { asm volatile("s_waitcnt vmcnt(0)" ::: "memory"); }
    __builtin_amdgcn_s_barrier();                  // tile kt landed for all waves
    __builtin_amdgcn_sched_barrier(0);
    __builtin_amdgcn_s_setprio(1);
#pragma unroll
    for (int kk = 0; kk < 2; ++kk) {
      bf16x8 af[8], bfr[4];
      const int kb = kk * 64 + ((lane >> 4) * 16);
#pragma unroll
      for (int m = 0; m < 8; ++m) {
        const int row = wm * 128 + m * 16 + (lane & 15);
        af[m] = *(const bf16x8*)((const char*)Al[cur] + ((row * 128 + kb) ^ ((row & 7) << 4)));
      }
#pragma unroll
      for (int n = 0; n < 4; ++n) {
        const int row = wn * 64 + n * 16 + (lane & 15);
        bfr[n] = *(const bf16x8*)((const char*)Bl[cur] + ((row * 128 + kb) ^ ((row & 7) << 4)));
      }
#pragma unroll
      for (int m = 0; m < 8; ++m)
#pragma unroll
        for (int n = 0; n < 4; ++n)
          acc[m][n] = __builtin_amdgcn_mfma_f32_16x16x32_bf16(af[m], bfr[n], acc[m][n], 0, 0, 0);
    }
    __builtin_amdgcn_s_setprio(0);
    __builtin_amdgcn_sched_barrier(0);
    __builtin_amdgcn_s_barrier();                  // all waves done reading buf[cur]
    if (kt < 14) STAGE(cur, (kt + 2) * 64);        // safe overwrite; stays in flight
  }
#undef STAGE

  // ---- epilogue: bias + sparse LoRA, fp32 store ----
  const int rg = lane >> 4, cl = lane & 15;
  const int baser = m0 + wm * 128, basec = n0 + wn * 64;
  float bs[4];
#pragma unroll
  for (int n = 0; n < 4; ++n) bs[n] = bias[basec + n * 16 + cl];
#pragma unroll
  for (int m = 0; m < 8; ++m)
#pragma unroll
    for (int j = 0; j < 4; ++j) {
      const int rr = baser + m * 16 + rg * 4 + j;
      const int2 id2 = *(const int2*)(ids + rr * 2);
      const float4 c0 = *(const float4*)(cvals + rr * 8);
      const float4 c1 = *(const float4*)(cvals + rr * 8 + 4);
      const float* u0b = lup + (size_t)id2.x * (D_DIM * 4);
      const float* u1b = lup + (size_t)id2.y * (D_DIM * 4);
#pragma unroll
      for (int n = 0; n < 4; ++n) {
        const int cc = basec + n * 16 + cl;
        float4 u0 = *(const float4*)(u0b + cc * 4);
        float4 u1 = *(const float4*)(u1b + cc * 4);
        float v = acc[m][n][j] + bs[n];
        v += c0.x * u0.x + c0.y * u0.y + c0.z * u0.z + c0.w * u0.w;
        v += c1.x * u1.x + c1.y * u1.y + c1.z * u1.z + c1.w * u1.w;
        out[(size_t)rr * D_DIM + cc] = v;
      }
    }
}

// ---------------- fallback GEMM (fp32 A, reg-staged) — R7-proven ------------
__global__ __launch_bounds__(256, 2)
void moe_gemm_f32(const float* __restrict__ x, const u16* __restrict__ Wb,
                  const float* __restrict__ bias, const int* __restrict__ ids,
                  const float* __restrict__ cvals, const float* __restrict__ lup,
                  float* __restrict__ out) {
  __shared__ u16 Al[128 * 64];
  __shared__ u16 Bl[128 * 64];
  const int tid = threadIdx.x, lane = tid & 63, wid = tid >> 6;
  const int wm = wid >> 1, wn = wid & 1;
  const int p = blockIdx.x;
  const int cx = p & 7, q = p >> 3;
  const int nb = q & 7, mb = cx * 16 + (q >> 3);
  const int m0 = mb * 128, n0 = nb * 128;
  f32x4 acc[4][4] = {};
  float4 av[8];
#pragma unroll
  for (int t = 0; t < 8; ++t) {
    int c = t * 256 + tid, row = c >> 4, k4 = c & 15;
    av[t] = *(const float4*)(x + (size_t)(m0 + row) * D_DIM + k4 * 4);
  }
#pragma unroll 1
  for (int kt = 0; kt < 16; ++kt) {
    const int k0 = kt * 64;
#pragma unroll
    for (int i = 0; i < 4; ++i) {
      int c = i * 256 + tid, row = c >> 3, kc = (c & 7) ^ (row & 7);
      __builtin_amdgcn_global_load_lds(
          (const __attribute__((address_space(1))) u32*)(Wb + (size_t)(n0 + row) * D_DIM + k0 + kc * 8),
          (__attribute__((address_space(3))) u32*)&Bl[c * 8], 16, 0, 0);
    }
#pragma unroll
    for (int t = 0; t < 8; ++t) {
      int c = t * 256 + tid, row = c >> 4, k4 = c & 15;
      int off = (row * 128 + k4 * 8) ^ ((row & 7) << 4);
      *(ushort4*)((char*)Al + off) =
          make_ushort4(f2bf(av[t].x), f2bf(av[t].y), f2bf(av[t].z), f2bf(av[t].w));
    }
    __syncthreads();
    if (kt < 15) {
#pragma unroll
      for (int t = 0; t < 8; ++t) {
        int c = t * 256 + tid, row = c >> 4, k4 = c & 15;
        av[t] = *(const float4*)(x + (size_t)(m0 + row) * D_DIM + (k0 + 64) + k4 * 4);
      }
    }
#pragma unroll
    for (int kk = 0; kk < 2; ++kk) {
      bf16x8 af[4], bfr[4];
      const int kb = kk * 64 + ((lane >> 4) * 16);
#pragma unroll
      for (int m = 0; m < 4; ++m) {
        int row = wm * 64 + m * 16 + (lane & 15);
        af[m] = *(const bf16x8*)((const char*)Al + ((row * 128 + kb) ^ ((row & 7) << 4)));
      }
#pragma unroll
      for (int n = 0; n < 4; ++n) {
        int row = wn * 64 + n * 16 + (lane & 15);
        bfr[n] = *(const bf16x8*)((const char*)Bl + ((row * 128 + kb) ^ ((row & 7) << 4)));
      }
#pragma unroll
      for (int m = 0; m < 4; ++m)
#pragma unroll
        for (int n = 0; n < 4; ++n)
          acc[m][n] = __builtin_amdgcn_mfma_f32_16x16x32_bf16(af[m], bfr[n], acc[m][n], 0, 0, 0);
    }
    __syncthreads();
  }
  const int rg = lane >> 4, cl = lane & 15;
  const int baser = m0 + wm * 64, basec = n0 + wn * 64;
  float bs[4];
#pragma unroll
  for (int n = 0; n < 4; ++n) bs[n] = bias[basec + n * 16 + cl];
#pragma unroll
  for (int m = 0; m < 4; ++m)
#pragma unroll
    for (int j = 0; j < 4; ++j) {
      const int rr = baser + m * 16 + rg * 4 + j;
      const int2 id2 = *(const int2*)(ids + rr * 2);
      const float4 c0 = *(const float4*)(cvals + rr * 8);
      const float4 c1 = *(const float4*)(cvals + rr * 8 + 4);
      const float* u0b = lup + (size_t)id2.x * (D_DIM * 4);
      const float* u1b = lup + (size_t)id2.y * (D_DIM * 4);
#pragma unroll
      for (int n = 0; n < 4; ++n) {
        const int cc = basec + n * 16 + cl;
        float4 u0 = *(const float4*)(u0b + cc * 4);
        float4 u1 = *(const float4*)(u1b + cc * 4);
        float v = acc[m][n][j] + bs[n];
        v += c0.x * u0.x + c0.y * u0.y + c0.z * u0.z + c0.w * u0.w;
        v += c1.x * u1.x + c1.y * u1.y + c1.z * u1.z + c1.w * u1.w;
        out[(size_t)rr * D_DIM + cc] = v;
      }
    }
}

extern "C" void kernel_launch(void* const* d_in, const int* in_sizes, int n_in,
                              void* d_out, int out_size, void* d_ws, size_t ws_size,
                              hipStream_t stream) {
  const float* x   = (const float*)d_in[0];
  const float* Wb_ = (const float*)d_in[1];
  const float* bb  = (const float*)d_in[2];
  const float* gW  = (const float*)d_in[3];
  const float* gb  = (const float*)d_in[4];
  const float* ld  = (const float*)d_in[5];
  const float* lup = (const float*)d_in[6];

  // ws (KB): Wbf 0-2048 | Bld 2048-2144 | ids 2144-2272 | cvals 2272-2784 |
  //          h_all 2784-5344 | xb 5632-38400  (~37.5 MB total)
  char* w = (char*)d_ws;
  u16*   Wbf   = (u16*)w;
  u16*   Bld   = (u16*)(w + 2048ull * 1024);
  int*   ids   = (int*)(w + 2144ull * 1024);
  float* cvals = (float*)(w + 2272ull * 1024);
  float* h_all = (float*)(w + 2784ull * 1024);
  const size_t need_full = (5632ull + 32768ull) * 1024;
  const bool full = ws_size >= need_full;
  u16* xb = full ? (u16*)(w + 5632ull * 1024) : nullptr;

  hipLaunchKernelGGL(conv_w,     dim3(512),  dim3(256), 0, stream, Wb_, Wbf);
  hipLaunchKernelGGL(prep_ldb,   dim3(48),   dim3(256), 0, stream, ld, Bld);
  hipLaunchKernelGGL(moe_prep_h, dim3(1024), dim3(256), 0, stream, x, Bld, h_all, xb);
  hipLaunchKernelGGL(moe_gate,   dim3(1024), dim3(256), 0, stream, x, gW, gb, h_all, ids, cvals);
  if (full)
    hipLaunchKernelGGL(moe_gemm_256, dim3(256), dim3(512), 0, stream,
                       xb, Wbf, bb, ids, cvals, lup, (float*)d_out);
  else
    hipLaunchKernelGGL(moe_gemm_f32, dim3(1024), dim3(256), 0, stream,
                       x, Wbf, bb, ids, cvals, lup, (float*)d_out);
}

// Round 11
// 119.258 us; speedup vs baseline: 1.0610x; 1.0516x over previous
//
#include <hip/hip_runtime.h>
#include <hip/hip_bf16.h>
#include <cstdint>
#include <cstddef>

// B=4, S=4096, D=1024, E=10, R=4, TOPK=2, SCALING=0.25
#define D_DIM 1024
#define E_NUM 10

typedef __attribute__((ext_vector_type(8))) short bf16x8;
typedef __attribute__((ext_vector_type(4))) float f32x4;
typedef unsigned short u16;
typedef unsigned int u32;

__device__ __forceinline__ u16 f2bf(float f) {
  union { float f; u32 u; } v; v.f = f;
  u32 r = v.u + 0x7fffu + ((v.u >> 16) & 1u);   // RNE
  return (u16)(r >> 16);
}
__device__ __forceinline__ float bf2f(u16 u) {
  union { u32 u; float f; } v; v.u = ((u32)u) << 16; return v.f;
}
__device__ __forceinline__ float dot4(float4 a, float4 b) {
  return a.x * b.x + a.y * b.y + a.z * b.z + a.w * b.w;
}

// ---------------- W_base fp32 -> bf16 (proven) ----------------
__global__ void conv_w(const float* __restrict__ W, u16* __restrict__ Wb) {
  const int i = (blockIdx.x * 256 + threadIdx.x) * 8;
  float4 a = *(const float4*)(W + i);
  float4 b = *(const float4*)(W + i + 4);
  *(ushort4*)(Wb + i)     = make_ushort4(f2bf(a.x), f2bf(a.y), f2bf(a.z), f2bf(a.w));
  *(ushort4*)(Wb + i + 4) = make_ushort4(f2bf(b.x), f2bf(b.y), f2bf(b.z), f2bf(b.w));
}

// ---------------- Bld[48][1024] bf16: rows 0-39 = lora_down, 40-47 = 0 ------
__global__ void prep_ldb(const float* __restrict__ ld, u16* __restrict__ Bld) {
  const int r = blockIdx.x;   // 48
  for (int c = threadIdx.x; c < D_DIM; c += 256)
    Bld[r * D_DIM + c] = (r < 40) ? f2bf(ld[r * D_DIM + c]) : (u16)0;
}

// ---------------- Ub[1024][64] bf16: Ub[o][j] = lup[j>>2][o][j&3], pad 0 ----
__global__ void prep_ub(const float* __restrict__ lup, u16* __restrict__ Ub) {
  const int g = blockIdx.x * 256 + threadIdx.x;   // 65536 threads
  const int o = g >> 6, j = g & 63;
  Ub[g] = (j < 40) ? f2bf(lup[(size_t)(j >> 2) * (D_DIM * 4) + o * 4 + (j & 3)]) : (u16)0;
}

// ---------------- h via MFMA, 4-way k-split across waves (R8-proven) --------
// NEW: h output stored as bf16 (hb).
__global__ __launch_bounds__(256)
void moe_prep_h(const float* __restrict__ x, const u16* __restrict__ Bld,
                u16* __restrict__ hb, u16* __restrict__ xb) {
  __shared__ u16 sX[4][16 * 64];
  __shared__ u16 sB[4][48 * 64];
  __shared__ float sP[4][3][16][17];

  const int tid = threadIdx.x, lane = tid & 63, w = tid >> 6;
  const int r0 = blockIdx.x * 16;
  const int kbase = w * 256;

  f32x4 acc[3] = {};

  float4 av[4];
#pragma unroll
  for (int i = 0; i < 2; ++i) {
    const int c = lane * 2 + i, row = c >> 3, kc = c & 7;
    const float* g = x + (size_t)(r0 + row) * D_DIM + kbase + kc * 8;
    av[i * 2]     = *(const float4*)g;
    av[i * 2 + 1] = *(const float4*)(g + 4);
  }

#pragma unroll 1
  for (int kt = 0; kt < 4; ++kt) {
    const int k0 = kbase + kt * 64;
#pragma unroll
    for (int i = 0; i < 6; ++i) {
      const int c = i * 64 + lane, row = c >> 3, kc = (c & 7) ^ (row & 7);
      __builtin_amdgcn_global_load_lds(
          (const __attribute__((address_space(1))) u32*)(Bld + (size_t)row * D_DIM + k0 + kc * 8),
          (__attribute__((address_space(3))) u32*)&sB[w][c * 8], 16, 0, 0);
    }
#pragma unroll
    for (int i = 0; i < 2; ++i) {
      const int c = lane * 2 + i, row = c >> 3, kc = c & 7;
      const float4 a = av[i * 2], b = av[i * 2 + 1];
      const ushort4 ha = make_ushort4(f2bf(a.x), f2bf(a.y), f2bf(a.z), f2bf(a.w));
      const ushort4 hb4 = make_ushort4(f2bf(b.x), f2bf(b.y), f2bf(b.z), f2bf(b.w));
      const int off = (row * 128 + kc * 16) ^ ((row & 7) << 4);
      *(ushort4*)((char*)sX[w] + off)     = ha;
      *(ushort4*)((char*)sX[w] + off + 8) = hb4;
      if (xb) {
        u16* dst = xb + (size_t)(r0 + row) * D_DIM + k0 + kc * 8;
        *(ushort4*)dst       = ha;
        *(ushort4*)(dst + 4) = hb4;
      }
    }
    __syncthreads();
    if (kt < 3) {
#pragma unroll
      for (int i = 0; i < 2; ++i) {
        const int c = lane * 2 + i, row = c >> 3, kc = c & 7;
        const float* g = x + (size_t)(r0 + row) * D_DIM + (k0 + 64) + kc * 8;
        av[i * 2]     = *(const float4*)g;
        av[i * 2 + 1] = *(const float4*)(g + 4);
      }
    }
#pragma unroll
    for (int kk = 0; kk < 2; ++kk) {
      const int kb = kk * 64 + ((lane >> 4) * 16);
      const int rA = lane & 15;
      const bf16x8 a0 = *(const bf16x8*)((const char*)sX[w] + ((rA * 128 + kb) ^ ((rA & 7) << 4)));
#pragma unroll
      for (int cf = 0; cf < 3; ++cf) {
        const int rB = cf * 16 + (lane & 15);
        const bf16x8 q = *(const bf16x8*)((const char*)sB[w] + ((rB * 128 + kb) ^ ((rB & 7) << 4)));
        acc[cf] = __builtin_amdgcn_mfma_f32_16x16x32_bf16(a0, q, acc[cf], 0, 0, 0);
      }
    }
    __syncthreads();
  }

#pragma unroll
  for (int cf = 0; cf < 3; ++cf)
#pragma unroll
    for (int j = 0; j < 4; ++j)
      sP[w][cf][(lane >> 4) * 4 + j][lane & 15] = acc[cf][j];
  __syncthreads();

  const int row = tid >> 4, c16 = tid & 15;
#pragma unroll
  for (int cf = 0; cf < 3; ++cf) {
    const int col = cf * 16 + c16;
    if (col < 40) {
      const float s = sP[0][cf][row][c16] + sP[1][cf][row][c16] +
                      sP[2][cf][row][c16] + sP[3][cf][row][c16];
      hb[(size_t)(r0 + row) * 40 + col] = f2bf(s);
    }
  }
}

// ---------------- gating (R9-proven fp32 math) -> dense coeff rows ----------
// cd[t][64] bf16: slot e*4+r = softmax_w(e) * SCALING * h[t][e*4+r] for top-2
// experts, 0 elsewhere (pad 40..63 = 0).
__global__ __launch_bounds__(256, 2)
void moe_gate(const float* __restrict__ x, const float* __restrict__ gW,
              const float* __restrict__ gb, const u16* __restrict__ hb,
              u16* __restrict__ cd) {
  const int tid = threadIdx.x, lane = tid & 63, w = tid >> 6;
  const int tb = blockIdx.x * 16 + w * 4;

  float4 xv[4][4];
#pragma unroll
  for (int tok = 0; tok < 4; ++tok)
#pragma unroll
    for (int j = 0; j < 4; ++j)
      xv[tok][j] = *(const float4*)(x + (size_t)(tb + tok) * D_DIM + j * 256 + lane * 4);

  float lg[4][E_NUM];
#pragma unroll
  for (int e = 0; e < E_NUM; ++e) {
    float a0 = 0.f, a1 = 0.f, a2 = 0.f, a3 = 0.f;
#pragma unroll
    for (int j = 0; j < 4; ++j) {
      const float4 wv = *(const float4*)(gW + e * D_DIM + j * 256 + lane * 4);
      a0 += dot4(xv[0][j], wv);
      a1 += dot4(xv[1][j], wv);
      a2 += dot4(xv[2][j], wv);
      a3 += dot4(xv[3][j], wv);
    }
#pragma unroll
    for (int o = 32; o; o >>= 1) {
      a0 += __shfl_xor(a0, o);
      a1 += __shfl_xor(a1, o);
      a2 += __shfl_xor(a2, o);
      a3 += __shfl_xor(a3, o);
    }
    const float be = gb[e];
    lg[0][e] = a0 + be;
    lg[1][e] = a1 + be;
    lg[2][e] = a2 + be;
    lg[3][e] = a3 + be;
  }

  if (lane < 4) {
    const int tok = lane, t = tb + tok;
    int e0 = 0; float v0 = lg[tok][0];
#pragma unroll
    for (int e = 1; e < E_NUM; ++e) if (lg[tok][e] > v0) { v0 = lg[tok][e]; e0 = e; }
    int e1 = -1; float v1 = -3.0e38f;
#pragma unroll
    for (int e = 0; e < E_NUM; ++e) if (e != e0 && lg[tok][e] > v1) { v1 = lg[tok][e]; e1 = e; }
    const float pp = expf(v1 - v0);
    const float inv = 1.f / (1.f + pp);
    const float s0 = inv * 0.25f, s1 = pp * inv * 0.25f;   // softmax * SCALING

    u16* dst = cd + (size_t)t * 64;
    const u16* hrow = hb + (size_t)t * 40;
#pragma unroll
    for (int e = 0; e < E_NUM; ++e) {
      const float we = (e == e0) ? s0 : ((e == e1) ? s1 : 0.f);
      const ushort4 hh = *(const ushort4*)(hrow + e * 4);
      *(ushort4*)(dst + e * 4) = make_ushort4(
          f2bf(bf2f(hh.x) * we), f2bf(bf2f(hh.y) * we),
          f2bf(bf2f(hh.z) * we), f2bf(bf2f(hh.w) * we));
    }
#pragma unroll
    for (int j = 40; j < 64; j += 4)
      *(ushort4*)(dst + j) = make_ushort4(0, 0, 0, 0);
  }
}

// ---------------- main GEMM: K = 16 tiles (x@W^T) + 1 tail tile (cd@U^T) ----
// 2ph double-buffered (R9 structure); epilogue = bias only.
__global__ __launch_bounds__(256, 2)
void moe_gemm_t(const u16* __restrict__ xb, const u16* __restrict__ Wbf,
                const u16* __restrict__ cd, const u16* __restrict__ Ub,
                const float* __restrict__ bias, float* __restrict__ out) {
  __shared__ u16 Al[2][128 * 64];
  __shared__ u16 Bl[2][128 * 64];

  const int tid = threadIdx.x, lane = tid & 63, wid = tid >> 6;
  const int wm = wid >> 1, wn = wid & 1;
  const int p = blockIdx.x;
  const int cx = p & 7, q = p >> 3;
  const int nb = q & 7, mb = cx * 16 + (q >> 3);
  const int m0 = mb * 128, n0 = nb * 128;

  int sc_row[4], sc_kc[4];
#pragma unroll
  for (int i = 0; i < 4; ++i) {
    const int c = i * 256 + tid;
    sc_row[i] = c >> 3;
    sc_kc[i]  = (c & 7) ^ (sc_row[i] & 7);
  }

  f32x4 acc[4][4] = {};

  auto STAGE = [&](int buf, int ktile) {
    const u16* As; const u16* Bs; size_t str; int ko;
    if (ktile < 16) {
      As = xb + (size_t)m0 * D_DIM; Bs = Wbf + (size_t)n0 * D_DIM;
      str = D_DIM; ko = ktile * 64;
    } else {
      As = cd + (size_t)m0 * 64; Bs = Ub + (size_t)n0 * 64;
      str = 64; ko = 0;
    }
#pragma unroll
    for (int i = 0; i < 4; ++i) {
      const int c = i * 256 + tid;
      __builtin_amdgcn_global_load_lds(
          (const __attribute__((address_space(1))) u32*)(As + (size_t)sc_row[i] * str + ko + sc_kc[i] * 8),
          (__attribute__((address_space(3))) u32*)&Al[buf][c * 8], 16, 0, 0);
    }
#pragma unroll
    for (int i = 0; i < 4; ++i) {
      const int c = i * 256 + tid;
      __builtin_amdgcn_global_load_lds(
          (const __attribute__((address_space(1))) u32*)(Bs + (size_t)sc_row[i] * str + ko + sc_kc[i] * 8),
          (__attribute__((address_space(3))) u32*)&Bl[buf][c * 8], 16, 0, 0);
    }
  };

  STAGE(0, 0);
  __syncthreads();

#pragma unroll 1
  for (int kt = 0; kt < 17; ++kt) {
    const int cur = kt & 1;
    if (kt < 16) STAGE(cur ^ 1, kt + 1);     // overlap with compute below
#pragma unroll
    for (int kk = 0; kk < 2; ++kk) {
      bf16x8 af[4], bfr[4];
      const int kb = kk * 64 + ((lane >> 4) * 16);
#pragma unroll
      for (int m = 0; m < 4; ++m) {
        const int row = wm * 64 + m * 16 + (lane & 15);
        af[m] = *(const bf16x8*)((const char*)Al[cur] + ((row * 128 + kb) ^ ((row & 7) << 4)));
      }
#pragma unroll
      for (int n = 0; n < 4; ++n) {
        const int row = wn * 64 + n * 16 + (lane & 15);
        bfr[n] = *(const bf16x8*)((const char*)Bl[cur] + ((row * 128 + kb) ^ ((row & 7) << 4)));
      }
#pragma unroll
      for (int m = 0; m < 4; ++m)
#pragma unroll
        for (int n = 0; n < 4; ++n)
          acc[m][n] = __builtin_amdgcn_mfma_f32_16x16x32_bf16(af[m], bfr[n], acc[m][n], 0, 0, 0);
    }
    __syncthreads();
  }

  // ---- epilogue: bias only, fp32 store ----
  const int rg = lane >> 4, cl = lane & 15;
  const int baser = m0 + wm * 64, basec = n0 + wn * 64;
  float bs[4];
#pragma unroll
  for (int n = 0; n < 4; ++n) bs[n] = bias[basec + n * 16 + cl];
#pragma unroll
  for (int m = 0; m < 4; ++m)
#pragma unroll
    for (int j = 0; j < 4; ++j) {
      const int rr = baser + m * 16 + rg * 4 + j;
#pragma unroll
      for (int n = 0; n < 4; ++n)
        out[(size_t)rr * D_DIM + basec + n * 16 + cl] = acc[m][n][j] + bs[n];
    }
}

extern "C" void kernel_launch(void* const* d_in, const int* in_sizes, int n_in,
                              void* d_out, int out_size, void* d_ws, size_t ws_size,
                              hipStream_t stream) {
  const float* x   = (const float*)d_in[0];
  const float* Wb_ = (const float*)d_in[1];
  const float* bb  = (const float*)d_in[2];
  const float* gW  = (const float*)d_in[3];
  const float* gb  = (const float*)d_in[4];
  const float* ld  = (const float*)d_in[5];
  const float* lup = (const float*)d_in[6];

  // ws (KB): Wbf 0-2048 | Ub 2048-2176 | Bld 2176-2272 | cd 2272-4320 |
  //          hb 4320-5600 | xb 5600-38368   (within the proven 38400 KB bound)
  char* w = (char*)d_ws;
  u16* Wbf = (u16*)w;
  u16* Ub  = (u16*)(w + 2048ull * 1024);
  u16* Bld = (u16*)(w + 2176ull * 1024);
  u16* cd  = (u16*)(w + 2272ull * 1024);
  u16* hb  = (u16*)(w + 4320ull * 1024);
  u16* xb  = (u16*)(w + 5600ull * 1024);

  hipLaunchKernelGGL(conv_w,     dim3(512),  dim3(256), 0, stream, Wb_, Wbf);
  hipLaunchKernelGGL(prep_ldb,   dim3(48),   dim3(256), 0, stream, ld, Bld);
  hipLaunchKernelGGL(prep_ub,    dim3(256),  dim3(256), 0, stream, lup, Ub);
  hipLaunchKernelGGL(moe_prep_h, dim3(1024), dim3(256), 0, stream, x, Bld, hb, xb);
  hipLaunchKernelGGL(moe_gate,   dim3(1024), dim3(256), 0, stream, x, gW, gb, hb, cd);
  hipLaunchKernelGGL(moe_gemm_t, dim3(1024), dim3(256), 0, stream,
                     xb, Wbf, cd, Ub, bb, (float*)d_out);
}